// Round 17
// baseline (125.331 us; speedup 1.0000x reference)
//
#include <hip/hip_runtime.h>
#include <math.h>

#define T_LEN 100
#define K_LEN 25
#define DLAT 64
#define DHID 128
#define AST 68
#define ZST 136   // zb row stride in shorts (bf16); 272B
#define ZTT 72    // h2T row stride in shorts; 144B

typedef __attribute__((ext_vector_type(8))) short bf16x8;
typedef __attribute__((ext_vector_type(4))) float f32x4v;

union ABu { bf16x8 v; unsigned u[4]; uint2 t[2]; };

// pack 2 f32 -> 2 bf16 (RNE) in one u32
__device__ __forceinline__ unsigned pk(float lo, float hi) {
    unsigned r;
    asm("v_cvt_pk_bf16_f32 %0, %1, %2" : "=v"(r) : "v"(lo), "v"(hi));
    return r;
}

// ---------------------------------------------------------------------------
// buildW: collapse Conv1d(1,64,25,pad=12) + Linear(100,1) into one matrix.
// ---------------------------------------------------------------------------
__global__ __launch_bounds__(256) void buildW(const float* __restrict__ conv_w,
                                              const float* __restrict__ conv_b,
                                              const float* __restrict__ fc1_w,
                                              const float* __restrict__ fc1_b,
                                              float* __restrict__ W,
                                              float* __restrict__ b2) {
    int idx = blockIdx.x * 256 + threadIdx.x;
    if (idx < 64 * T_LEN) {
        int c = idx / T_LEN, i = idx % T_LEN;
        int t0 = i - 12 > 0 ? i - 12 : 0;
        int t1 = i + 12 < T_LEN - 1 ? i + 12 : T_LEN - 1;
        float acc = 0.f;
        for (int t = t0; t <= t1; ++t)
            acc += fc1_w[t] * conv_w[c * K_LEN + (i - t + 12)];
        W[idx] = acc;
    } else if (idx < 64 * T_LEN + 64) {
        int c = idx - 64 * T_LEN;
        float S = 0.f;
        for (int t = 0; t < T_LEN; ++t) S += fc1_w[t];
        b2[c] = conv_b[c] * S + fc1_b[0];
    }
}

// ---------------------------------------------------------------------------
// phaseCF9: r16's MFMA-agg with the D-layout store made ASSUMPTION-FREE.
// r16's failure signature (Sg-invariant, Qg-corrupting) matches a wrong D
// ROW map — the one layout fact r15's reduce-only part2 never verified.
// Fix: discover the (lane,reg)->(row,col) map at runtime with two label
// MFMAs (A=row-label,B=1 -> D=32*row ; A=1,B=col-label -> D=32*col), then
// scatter agg by the DISCOVERED indices. Degenerates to the documented map
// if that map is right. Labels<=15: bf16/f32 exact.
// Everything else identical to r16 (encoder+h2T, part2 = r15-verified form).
// ---------------------------------------------------------------------------
__global__ __launch_bounds__(512, 4) void phaseCF9(const float* __restrict__ x,
                                                   const int* __restrict__ ei,
                                                   const float* __restrict__ Wm,
                                                   const float* __restrict__ b2,
                                                   const float* __restrict__ rel_w,
                                                   const float* __restrict__ rel_b,
                                                   const float* __restrict__ root_w,
                                                   float* __restrict__ Sg,
                                                   float* __restrict__ Qg,
                                                   int E, int G) {
    __shared__ unsigned Asu[64 * AST];        // 17408 B
    __shared__ unsigned short zb[64 * ZST];   // 17408 B: [agg(0..64) | h2(64..128)]
    __shared__ unsigned short h2T[64 * ZTT];  //  9216 B: h2T[c][n]

    int tid = threadIdx.x;
    int bid = blockIdx.x;
    int lane = tid & 63;
    int w = __builtin_amdgcn_readfirstlane(tid >> 6);  // 0..7, uniform

    // bijective XCD swizzle (m204)
    int q = G >> 3, r = G & 7;
    int xc = bid & 7, o = bid >> 3;
    int g = (xc < r ? xc * (q + 1) : r * (q + 1) + (xc - r) * q) + o;

    int epg = E / G;
    bool fast = (epg == 2048);

    // 0. issue strided edge loads EARLY (drain after encoder)
    int es0 = 0, es1 = 0, es2 = 0, es3 = 0;
    int ed0 = 0, ed1 = 0, ed2 = 0, ed3 = 0;
    if (fast) {
        int e0 = g + tid * G;
        int st = 512 * G;
        es0 = ei[e0];            ed0 = ei[E + e0];
        es1 = ei[e0 + st];       ed1 = ei[E + e0 + st];
        es2 = ei[e0 + 2 * st];   ed2 = ei[E + e0 + 2 * st];
        es3 = ei[e0 + 3 * st];   ed3 = ei[E + e0 + 3 * st];
    }

    // zero adjacency counters
    for (int idx = tid; idx < 64 * AST; idx += 512) Asu[idx] = 0u;

    // 1. encoder: wave w -> channels [8w, 8w+8) for node = lane.
    {
        const float4* __restrict__ xp =
            (const float4*)(x + (size_t)(g * 64 + lane) * T_LEN);
        const float* __restrict__ Wb = Wm + w * 8 * T_LEN;  // uniform -> s_load
        float acc[8];
#pragma unroll
        for (int c = 0; c < 8; ++c) acc[c] = 0.f;
        for (int tq = 0; tq < T_LEN / 4; ++tq) {
            float4 xv = xp[tq];
#pragma unroll
            for (int c = 0; c < 8; ++c) {
                const float* wr = Wb + c * T_LEN + tq * 4;
                acc[c] += xv.x * wr[0] + xv.y * wr[1] + xv.z * wr[2] + xv.w * wr[3];
            }
        }
#pragma unroll
        for (int c = 0; c < 8; ++c) acc[c] += b2[w * 8 + c];
        uint4 uv = {pk(acc[0], acc[1]), pk(acc[2], acc[3]),
                    pk(acc[4], acc[5]), pk(acc[6], acc[7])};
        *(uint4*)&zb[lane * ZST + 64 + w * 8] = uv;
#pragma unroll
        for (int c = 0; c < 8; ++c)
            h2T[(w * 8 + c) * ZTT + lane] = (unsigned short)pk(acc[c], acc[c]);
    }
    __syncthreads();  // S1

    // 2. edge counting via LDS atomics
    if (fast) {
        atomicAdd(&Asu[(ed0 & 63) * AST + (es0 & 63)], 1u);
        atomicAdd(&Asu[(ed1 & 63) * AST + (es1 & 63)], 1u);
        atomicAdd(&Asu[(ed2 & 63) * AST + (es2 & 63)], 1u);
        atomicAdd(&Asu[(ed3 & 63) * AST + (es3 & 63)], 1u);
    } else {
        for (int k = tid; k < epg; k += 512) {
            int e = g + k * G;
            atomicAdd(&Asu[(ei[E + e] & 63) * AST + (ei[e] & 63)], 1u);
        }
    }
    __syncthreads();  // S2

    // 3. agg via MFMA + runtime D-layout discovery.
    {
        const int l15 = lane & 15, lg = lane >> 4;
        const int mb = (w >> 1) * 16;
        const int cb = (w & 1) * 32;
        const int n = mb + l15;

        // ---- discover (lane,reg) -> (row,col) of D, assumption-free ----
        ABu Alab, Blab, Ones;
        unsigned labp = pk((float)l15, (float)l15);
        unsigned onep = pk(1.f, 1.f);
#pragma unroll
        for (int i = 0; i < 4; ++i) { Alab.u[i] = labp; Ones.u[i] = onep; Blab.u[i] = labp; }
        f32x4v dr = {0.f, 0.f, 0.f, 0.f};
        f32x4v dc = {0.f, 0.f, 0.f, 0.f};
        dr = __builtin_amdgcn_mfma_f32_16x16x32_bf16(Alab.v, Ones.v, dr, 0, 0, 0);
        dc = __builtin_amdgcn_mfma_f32_16x16x32_bf16(Ones.v, Blab.v, dc, 0, 0, 0);

        f32x4v e0 = {0.f, 0.f, 0.f, 0.f};
        f32x4v e1 = e0;
#pragma unroll
        for (int kk = 0; kk < 2; ++kk) {
            uint4 ua = *(const uint4*)&Asu[n * AST + kk * 32 + lg * 4];
            uint4 ub = *(const uint4*)&Asu[n * AST + kk * 32 + lg * 4 + 16];
            ABu A;
            A.u[0] = pk((float)ua.x, (float)ua.y);
            A.u[1] = pk((float)ua.z, (float)ua.w);
            A.u[2] = pk((float)ub.x, (float)ub.y);
            A.u[3] = pk((float)ub.z, (float)ub.w);
            ABu B0, B1;
            B0.t[0] = *(const uint2*)&h2T[(cb + l15) * ZTT + kk * 32 + lg * 4];
            B0.t[1] = *(const uint2*)&h2T[(cb + l15) * ZTT + kk * 32 + lg * 4 + 16];
            B1.t[0] = *(const uint2*)&h2T[(cb + 16 + l15) * ZTT + kk * 32 + lg * 4];
            B1.t[1] = *(const uint2*)&h2T[(cb + 16 + l15) * ZTT + kk * 32 + lg * 4 + 16];
            e0 = __builtin_amdgcn_mfma_f32_16x16x32_bf16(A.v, B0.v, e0, 0, 0, 0);
            e1 = __builtin_amdgcn_mfma_f32_16x16x32_bf16(A.v, B1.v, e1, 0, 0, 0);
        }
        // scatter by DISCOVERED (row,col) labels: rr = row-label of this slot
        // (which loaded A-row it holds), nc = col-label (which B-col).
#pragma unroll
        for (int e = 0; e < 4; ++e) {
            int rr = mb + (int)(dr[e] * 0.03125f + 0.5f);
            int nc = (int)(dc[e] * 0.03125f + 0.5f);
            zb[rr * ZST + cb + nc] = (unsigned short)pk(e0[e], e0[e]);
            zb[rr * ZST + cb + 16 + nc] = (unsigned short)pk(e1[e], e1[e]);
        }
    }
    __syncthreads();  // S3

    // 4. part2 via MFMA (r15-verified form): wave w -> j in [16w,16w+16).
    {
        const int l15 = lane & 15, lg = lane >> 4;
        const int j = w * 16 + l15;

        ABu B[4];
#pragma unroll
        for (int kk = 0; kk < 4; ++kk) {
            const float* src = (kk < 2)
                ? (rel_w + (size_t)j * DLAT + kk * 32)
                : (root_w + (size_t)j * DLAT + (kk - 2) * 32);
            float4 f0 = *(const float4*)(src + lg * 4);
            float4 f1 = *(const float4*)(src + lg * 4 + 16);
            B[kk].u[0] = pk(f0.x, f0.y);
            B[kk].u[1] = pk(f0.z, f0.w);
            B[kk].u[2] = pk(f1.x, f1.y);
            B[kk].u[3] = pk(f1.z, f1.w);
        }

        f32x4v d0 = {0.f, 0.f, 0.f, 0.f};
        f32x4v d1 = d0, d2 = d0, d3 = d0;
#pragma unroll
        for (int kk = 0; kk < 4; ++kk) {
            int cbs = kk * 32 + lg * 4;
            ABu a0_, a1_, a2_, a3_;
            a0_.t[0] = *(const uint2*)&zb[(0 * 16 + l15) * ZST + cbs];
            a0_.t[1] = *(const uint2*)&zb[(0 * 16 + l15) * ZST + cbs + 16];
            a1_.t[0] = *(const uint2*)&zb[(1 * 16 + l15) * ZST + cbs];
            a1_.t[1] = *(const uint2*)&zb[(1 * 16 + l15) * ZST + cbs + 16];
            a2_.t[0] = *(const uint2*)&zb[(2 * 16 + l15) * ZST + cbs];
            a2_.t[1] = *(const uint2*)&zb[(2 * 16 + l15) * ZST + cbs + 16];
            a3_.t[0] = *(const uint2*)&zb[(3 * 16 + l15) * ZST + cbs];
            a3_.t[1] = *(const uint2*)&zb[(3 * 16 + l15) * ZST + cbs + 16];
            d0 = __builtin_amdgcn_mfma_f32_16x16x32_bf16(a0_.v, B[kk].v, d0, 0, 0, 0);
            d1 = __builtin_amdgcn_mfma_f32_16x16x32_bf16(a1_.v, B[kk].v, d1, 0, 0, 0);
            d2 = __builtin_amdgcn_mfma_f32_16x16x32_bf16(a2_.v, B[kk].v, d2, 0, 0, 0);
            d3 = __builtin_amdgcn_mfma_f32_16x16x32_bf16(a3_.v, B[kk].v, d3, 0, 0, 0);
        }

        float rb = rel_b[j];
        float s = 0.f, qm = 0.f;
#pragma unroll
        for (int e = 0; e < 4; ++e) { float ov = d0[e] + rb; s += ov; qm += ov * ov; }
#pragma unroll
        for (int e = 0; e < 4; ++e) { float ov = d1[e] + rb; s += ov; qm += ov * ov; }
#pragma unroll
        for (int e = 0; e < 4; ++e) { float ov = d2[e] + rb; s += ov; qm += ov * ov; }
#pragma unroll
        for (int e = 0; e < 4; ++e) { float ov = d3[e] + rb; s += ov; qm += ov * ov; }
        s += __shfl_xor(s, 16);  qm += __shfl_xor(qm, 16);
        s += __shfl_xor(s, 32);  qm += __shfl_xor(qm, 32);
        if (lg == 0) {
            Sg[(size_t)g * DHID + j] = s;
            Qg[(size_t)g * DHID + j] = qm;
        }
    }
}

// ---------------------------------------------------------------------------
// Phase D: BN stats per channel -> a[j], b[j] (scale/shift)
// ---------------------------------------------------------------------------
__global__ __launch_bounds__(256) void phaseD2(const float* __restrict__ Sg,
                                               const float* __restrict__ Qg,
                                               const float* __restrict__ gamma,
                                               const float* __restrict__ beta,
                                               float* __restrict__ ab,
                                               int G, int N) {
    int j = blockIdx.x;
    int t = threadIdx.x;
    float s = 0.f, q = 0.f;
    for (int g = t; g < G; g += 256) {
        s += Sg[g * DHID + j];
        q += Qg[g * DHID + j];
    }
#pragma unroll
    for (int off = 32; off; off >>= 1) {
        s += __shfl_xor(s, off);
        q += __shfl_xor(q, off);
    }
    __shared__ float rs[4], rq[4];
    int wv = t >> 6;
    if ((t & 63) == 0) { rs[wv] = s; rq[wv] = q; }
    __syncthreads();
    if (t == 0) {
        s = rs[0] + rs[1] + rs[2] + rs[3];
        q = rq[0] + rq[1] + rq[2] + rq[3];
        float inv_n = 1.f / (float)N;
        float mean = s * inv_n;
        float var = q * inv_n - mean * mean;
        float a = rsqrtf(var + 1e-5f) * gamma[j];
        float b = beta[j] - mean * a;
        ab[j] = a;
        ab[DHID + j] = b;
    }
}

// ---------------------------------------------------------------------------
// Phase E: pooled = (a^2 Q + 2ab S)/64 + b^2 ; log(clamp) ; fc2 ; sigmoid
// ---------------------------------------------------------------------------
__global__ __launch_bounds__(128) void phaseE(const float* __restrict__ Sg,
                                              const float* __restrict__ Qg,
                                              const float* __restrict__ ab,
                                              const float* __restrict__ fc2_w,
                                              const float* __restrict__ fc2_b,
                                              float* __restrict__ y) {
    int g = blockIdx.x;
    int j = threadIdx.x;
    __shared__ float ps[DHID];
    float a = ab[j], b = ab[DHID + j];
    float S = Sg[g * DHID + j], Q = Qg[g * DHID + j];
    float pooled = (a * a * Q + 2.f * a * b * S) * (1.f / 64.f) + b * b;
    pooled = fmaxf(pooled, 1e-6f);
    ps[j] = logf(pooled);
    __syncthreads();
    if (j < 3) {
        float acc = fc2_b[j];
        for (int c = 0; c < DHID; ++c) acc += ps[c] * fc2_w[j * DHID + c];
        y[g * 3 + j] = 1.f / (1.f + expf(-acc));
    }
}

// ---------------------------------------------------------------------------
extern "C" void kernel_launch(void* const* d_in, const int* in_sizes, int n_in,
                              void* d_out, int out_size, void* d_ws, size_t ws_size,
                              hipStream_t stream) {
    const float* x      = (const float*)d_in[0];
    const int*   ei     = (const int*)d_in[1];
    const float* conv_w = (const float*)d_in[3];
    const float* conv_b = (const float*)d_in[4];
    const float* fc1_w  = (const float*)d_in[5];
    const float* fc1_b  = (const float*)d_in[6];
    const float* rel_w  = (const float*)d_in[7];
    const float* rel_b  = (const float*)d_in[8];
    const float* root_w = (const float*)d_in[9];
    const float* gamma  = (const float*)d_in[10];
    const float* beta   = (const float*)d_in[11];
    const float* fc2_w  = (const float*)d_in[12];
    const float* fc2_b  = (const float*)d_in[13];
    float* y = (float*)d_out;

    int N = in_sizes[2];       // 32768
    int E = in_sizes[1] / 2;   // 1048576
    int G = N / 64;            // 512

    float* Sg = (float*)d_ws;                  // G*128
    float* Qg = Sg + (size_t)G * DHID;         // G*128
    float* ab = Qg + (size_t)G * DHID;         // 2*128
    float* Wm = ab + 2 * DHID;                 // 64*100
    float* b2 = Wm + 64 * T_LEN;               // 64

    buildW<<<26, 256, 0, stream>>>(conv_w, conv_b, fc1_w, fc1_b, Wm, b2);
    phaseCF9<<<G, 512, 0, stream>>>(x, ei, Wm, b2, rel_w, rel_b, root_w,
                                    Sg, Qg, E, G);
    phaseD2<<<DHID, 256, 0, stream>>>(Sg, Qg, gamma, beta, ab, G, N);
    phaseE<<<G, DHID, 0, stream>>>(Sg, Qg, ab, fc2_w, fc2_b, y);
}